// Round 5
// baseline (659.411 us; speedup 1.0000x reference)
//
#include <hip/hip_runtime.h>
#include <hip/hip_bf16.h>
#include <hip/hip_fp16.h>
#include <cstdint>
#include <cstddef>

typedef int v16i __attribute__((ext_vector_type(16), aligned(8)));

// ---------------- CSR build ----------------

__global__ __launch_bounds__(256) void k_count(const int* __restrict__ dst, int* __restrict__ cnt, int E) {
    int i = blockIdx.x * blockDim.x + threadIdx.x;
    int stride = gridDim.x * blockDim.x;
    for (; i < E; i += stride) atomicAdd(&cnt[dst[i]], 1);
}

// per-block exclusive scan of (cnt[i]+1), block totals to partials; also dinv = rsqrt(deg)
__global__ __launch_bounds__(256) void k_scan_a(const int* __restrict__ cnt, int* __restrict__ offs,
                                                int* __restrict__ partials, float* __restrict__ dinv, int N) {
    __shared__ int sh[256];
    int t = threadIdx.x;
    int i = blockIdx.x * 256 + t;
    int v = (i < N) ? (cnt[i] + 1) : 0;
    sh[t] = v;
    __syncthreads();
    for (int d = 1; d < 256; d <<= 1) {
        int add = (t >= d) ? sh[t - d] : 0;
        __syncthreads();
        sh[t] += add;
        __syncthreads();
    }
    if (i < N) {
        offs[i] = sh[t] - v;       // exclusive within block
        dinv[i] = rsqrtf((float)v);
    }
    if (t == 255) partials[blockIdx.x] = sh[255];
}

// single-block inclusive scan of partials (nb <= 512)
__global__ __launch_bounds__(512) void k_scan_b(int* __restrict__ partials, int nb) {
    __shared__ int sh[512];
    int t = threadIdx.x;
    int v = (t < nb) ? partials[t] : 0;
    sh[t] = v;
    __syncthreads();
    for (int d = 1; d < 512; d <<= 1) {
        int add = (t >= d) ? sh[t - d] : 0;
        __syncthreads();
        sh[t] += add;
        __syncthreads();
    }
    if (t < nb) partials[t] = sh[t];
}

__global__ __launch_bounds__(256) void k_scan_c(int* __restrict__ offs, const int* __restrict__ partials,
                                                int N, int nb) {
    int i = blockIdx.x * 256 + threadIdx.x;
    if (i < N) {
        int b = i >> 8;
        if (b > 0) offs[i] += partials[b - 1];
    } else if (i == N) {
        offs[N] = partials[nb - 1];
    }
}

// cur[] pre-initialized to a copy of offs[] -> one fewer random read per edge
__global__ __launch_bounds__(256) void k_fill(const int* __restrict__ src, const int* __restrict__ dst,
                                              int* __restrict__ cur,
                                              const float* __restrict__ dinv,
                                              int2* __restrict__ cpack, int E) {
    int i = blockIdx.x * blockDim.x + threadIdx.x;
    int stride = gridDim.x * blockDim.x;
    for (; i < E; i += stride) {
        int s = src[i], d = dst[i];
        int pos = atomicAdd(&cur[d], 1);
        cpack[pos] = make_int2(s, __float_as_int(dinv[s] * dinv[d]));
    }
}

__global__ __launch_bounds__(256) void k_fill_loops(int* __restrict__ cur,
                                                    const float* __restrict__ dinv,
                                                    int2* __restrict__ cpack, int N) {
    int i = blockIdx.x * blockDim.x + threadIdx.x;
    if (i < N) {
        int pos = atomicAdd(&cur[i], 1);
        float di = dinv[i];
        cpack[pos] = make_int2(i, __float_as_int(di * di));
    }
}

// ---------------- node features: x = [emb[label], MLP(bbox)] -> fp16 ----------------

__global__ __launch_bounds__(256) void k_feat(const int* __restrict__ label, const float* __restrict__ bbox,
                                              const float* __restrict__ emb,
                                              const float* __restrict__ w1, const float* __restrict__ b1,
                                              const float* __restrict__ w2, const float* __restrict__ b2,
                                              __half* __restrict__ X, int N) {
    __shared__ float w1s[4 * 64];
    __shared__ float b1s[64], b2s[64];
    __shared__ float w2s[64 * 64];
    __shared__ float h1s[4][64];
    int t = threadIdx.x;
    if (t < 256) w1s[t] = w1[t];
    if (t < 64) { b1s[t] = b1[t]; b2s[t] = b2[t]; }
    for (int i = t; i < 64 * 64; i += 256) w2s[i] = w2[i];
    __syncthreads();

    int wave = t >> 6, lane = t & 63;
    int node = blockIdx.x * 4 + wave;
    bool ok = node < N;

    float h1 = 0.f;
    if (ok) {
        float bb0 = bbox[node * 4 + 0];
        float bb1 = bbox[node * 4 + 1];
        float bb2 = bbox[node * 4 + 2];
        float bb3 = bbox[node * 4 + 3];
        h1 = bb0 * w1s[0 * 64 + lane] + bb1 * w1s[1 * 64 + lane]
           + bb2 * w1s[2 * 64 + lane] + bb3 * w1s[3 * 64 + lane] + b1s[lane];
        h1 = fmaxf(h1, 0.f);
    }
    h1s[wave][lane] = h1;
    __syncthreads();

    if (ok) {
        float acc = b2s[lane];
        #pragma unroll 8
        for (int k = 0; k < 64; ++k) acc += h1s[wave][k] * w2s[k * 64 + lane];
        int lb = label[node];
        X[(size_t)node * 128 + lane] = __float2half(emb[(size_t)lb * 64 + lane]);
        X[(size_t)node * 128 + 64 + lane] = __float2half(acc);
    }
}

// ---------------- fused layer: Y = relu?( (A_hat @ X) @ W + b ) ----------------
// X fp16 [N][128] (row = 16 x uint4 = 256 B). Block = 256 thr = 4 waves = 32 nodes.
// Phase 1: wave handles 1 node at a time with 64 lanes = 4 groups x 16 lanes;
//   edge list scalar-loaded (SMEM) 8 edges/iter; group g gathers edges 2g,2g+1
//   as dwordx4 (full row per 16 lanes); cross-group shfl_xor reduce per node.
// Phase 2: Zl[32][132] @ W (W direct from global), bias+relu, fp16/fp32 out.

__device__ __forceinline__ int sel4(int a, int b, int c, int d, int g) {
    int ab = (g & 1) ? b : a;
    int cd = (g & 1) ? d : c;
    return (g & 2) ? cd : ab;
}

template <int OUT_HALF>
__global__ __launch_bounds__(256) void k_agg_gemm(const uint4* __restrict__ X4, const int* __restrict__ offs,
                                                  const int2* __restrict__ cpack,
                                                  const float* __restrict__ W, const float* __restrict__ bias,
                                                  void* __restrict__ Yv, int N, int do_relu) {
    __shared__ float Zl[32][132];   // row stride 132: 16B-aligned rows

    int t = threadIdx.x;
    int lane = t & 63;
    int wv = t >> 6;
    int grp = lane >> 4, li = lane & 15;
    int nb0 = __builtin_amdgcn_readfirstlane(blockIdx.x * 32 + ((t >> 6) << 3));

    int offv[9];
    #pragma unroll
    for (int j = 0; j < 9; ++j) {
        int idx = nb0 + j; idx = idx > N ? N : idx;
        offv[j] = offs[idx];           // uniform address -> scalar load
    }

    // ---- phase 1 ----
    #pragma unroll
    for (int nn = 0; nn < 8; ++nn) {
        int node = nb0 + nn;
        if (node >= N) break;
        int i0 = offv[nn], i1 = offv[nn + 1];
        float acc[8];
        #pragma unroll
        for (int k = 0; k < 8; ++k) acc[k] = 0.f;

        for (int e = i0; e < i1; e += 8) {        // e uniform -> cpack block scalar-loaded
            v16i blk = *(const v16i*)(cpack + e); // 8 (src,norm) pairs in SGPRs
            int sA  = sel4(blk[0], blk[4], blk[8],  blk[12], grp);
            int wAi = sel4(blk[1], blk[5], blk[9],  blk[13], grp);
            int sB  = sel4(blk[2], blk[6], blk[10], blk[14], grp);
            int wBi = sel4(blk[3], blk[7], blk[11], blk[15], grp);
            int eA = e + 2 * grp;
            float wA = (eA     < i1) ? __int_as_float(wAi) : 0.f;
            float wB = (eA + 1 < i1) ? __int_as_float(wBi) : 0.f;
            uint4 hA = X4[(size_t)sA * 16 + li];
            uint4 hB = X4[(size_t)sB * 16 + li];
            {
                float2 f;
                f = __half22float2(*(const __half2*)&hA.x); acc[0] += f.x * wA; acc[1] += f.y * wA;
                f = __half22float2(*(const __half2*)&hA.y); acc[2] += f.x * wA; acc[3] += f.y * wA;
                f = __half22float2(*(const __half2*)&hA.z); acc[4] += f.x * wA; acc[5] += f.y * wA;
                f = __half22float2(*(const __half2*)&hA.w); acc[6] += f.x * wA; acc[7] += f.y * wA;
                f = __half22float2(*(const __half2*)&hB.x); acc[0] += f.x * wB; acc[1] += f.y * wB;
                f = __half22float2(*(const __half2*)&hB.y); acc[2] += f.x * wB; acc[3] += f.y * wB;
                f = __half22float2(*(const __half2*)&hB.z); acc[4] += f.x * wB; acc[5] += f.y * wB;
                f = __half22float2(*(const __half2*)&hB.w); acc[6] += f.x * wB; acc[7] += f.y * wB;
            }
        }

        // cross-group reduce: lanes l, l^16, l^32, l^48 hold partials of the same cols
        #pragma unroll
        for (int k = 0; k < 8; ++k) {
            float v = acc[k];
            v += __shfl_xor(v, 16);
            v += __shfl_xor(v, 32);
            acc[k] = v;
        }
        if (grp == 0) {
            int row = (wv << 3) + nn;
            *(float4*)&Zl[row][li * 8]     = make_float4(acc[0], acc[1], acc[2], acc[3]);
            *(float4*)&Zl[row][li * 8 + 4] = make_float4(acc[4], acc[5], acc[6], acc[7]);
        }
    }

    __syncthreads();   // Zl complete

    // ---- phase 2: Y[32][128] = Zl @ W; thread = 2 rows x 8 cols ----
    int rowg = t >> 4;   // rows 2*rowg, 2*rowg+1
    int colg = t & 15;   // cols colg*8 .. +7
    float a0[8], a1[8];
    #pragma unroll
    for (int j = 0; j < 8; ++j) { a0[j] = 0.f; a1[j] = 0.f; }

    const float* Zr0 = &Zl[rowg * 2 + 0][0];
    const float* Zr1 = &Zl[rowg * 2 + 1][0];

    #pragma unroll 4
    for (int k0 = 0; k0 < 128; k0 += 4) {
        float4 z0 = *(const float4*)&Zr0[k0];
        float4 z1 = *(const float4*)&Zr1[k0];
        #pragma unroll
        for (int j = 0; j < 4; ++j) {
            int k = k0 + j;
            float zz0 = j == 0 ? z0.x : j == 1 ? z0.y : j == 2 ? z0.z : z0.w;
            float zz1 = j == 0 ? z1.x : j == 1 ? z1.y : j == 2 ? z1.z : z1.w;
            float4 w0 = *(const float4*)&W[k * 128 + colg * 8];
            float4 w1 = *(const float4*)&W[k * 128 + colg * 8 + 4];
            a0[0] += zz0 * w0.x; a0[1] += zz0 * w0.y; a0[2] += zz0 * w0.z; a0[3] += zz0 * w0.w;
            a0[4] += zz0 * w1.x; a0[5] += zz0 * w1.y; a0[6] += zz0 * w1.z; a0[7] += zz0 * w1.w;
            a1[0] += zz1 * w0.x; a1[1] += zz1 * w0.y; a1[2] += zz1 * w0.z; a1[3] += zz1 * w0.w;
            a1[4] += zz1 * w1.x; a1[5] += zz1 * w1.y; a1[6] += zz1 * w1.z; a1[7] += zz1 * w1.w;
        }
    }

    float4 bv0 = *(const float4*)&bias[colg * 8];
    float4 bv1 = *(const float4*)&bias[colg * 8 + 4];
    a0[0] += bv0.x; a0[1] += bv0.y; a0[2] += bv0.z; a0[3] += bv0.w;
    a0[4] += bv1.x; a0[5] += bv1.y; a0[6] += bv1.z; a0[7] += bv1.w;
    a1[0] += bv0.x; a1[1] += bv0.y; a1[2] += bv0.z; a1[3] += bv0.w;
    a1[4] += bv1.x; a1[5] += bv1.y; a1[6] += bv1.z; a1[7] += bv1.w;
    if (do_relu) {
        #pragma unroll
        for (int j = 0; j < 8; ++j) { a0[j] = fmaxf(a0[j], 0.f); a1[j] = fmaxf(a1[j], 0.f); }
    }

    int node0 = blockIdx.x * 32 + rowg * 2;
    if (OUT_HALF) {
        __half* Yh = (__half*)Yv;
        if (node0 < N) {
            __half2 p0 = __float22half2_rn(make_float2(a0[0], a0[1]));
            __half2 p1 = __float22half2_rn(make_float2(a0[2], a0[3]));
            __half2 p2 = __float22half2_rn(make_float2(a0[4], a0[5]));
            __half2 p3 = __float22half2_rn(make_float2(a0[6], a0[7]));
            uint4 pk;
            pk.x = *(unsigned int*)&p0; pk.y = *(unsigned int*)&p1;
            pk.z = *(unsigned int*)&p2; pk.w = *(unsigned int*)&p3;
            *(uint4*)(Yh + (size_t)node0 * 128 + colg * 8) = pk;
        }
        if (node0 + 1 < N) {
            __half2 p0 = __float22half2_rn(make_float2(a1[0], a1[1]));
            __half2 p1 = __float22half2_rn(make_float2(a1[2], a1[3]));
            __half2 p2 = __float22half2_rn(make_float2(a1[4], a1[5]));
            __half2 p3 = __float22half2_rn(make_float2(a1[6], a1[7]));
            uint4 pk;
            pk.x = *(unsigned int*)&p0; pk.y = *(unsigned int*)&p1;
            pk.z = *(unsigned int*)&p2; pk.w = *(unsigned int*)&p3;
            *(uint4*)(Yh + (size_t)(node0 + 1) * 128 + colg * 8) = pk;
        }
    } else {
        float* Yf = (float*)Yv;
        if (node0 < N) {
            float4* out = (float4*)(Yf + (size_t)node0 * 128 + colg * 8);
            out[0] = make_float4(a0[0], a0[1], a0[2], a0[3]);
            out[1] = make_float4(a0[4], a0[5], a0[6], a0[7]);
        }
        if (node0 + 1 < N) {
            float4* out = (float4*)(Yf + (size_t)(node0 + 1) * 128 + colg * 8);
            out[0] = make_float4(a1[0], a1[1], a1[2], a1[3]);
            out[1] = make_float4(a1[4], a1[5], a1[6], a1[7]);
        }
    }
}

// ---------------- launch ----------------

extern "C" void kernel_launch(void* const* d_in, const int* in_sizes, int n_in,
                              void* d_out, int out_size, void* d_ws, size_t ws_size,
                              hipStream_t stream) {
    const int*   label = (const int*)d_in[0];
    const float* bbox  = (const float*)d_in[1];
    const int*   eidx  = (const int*)d_in[2];
    const float* emb   = (const float*)d_in[3];
    const float* w1    = (const float*)d_in[4];
    const float* b1    = (const float*)d_in[5];
    const float* w2    = (const float*)d_in[6];
    const float* b2    = (const float*)d_in[7];
    const float* wg0   = (const float*)d_in[8];
    const float* bg0   = (const float*)d_in[9];
    const float* wg1   = (const float*)d_in[10];
    const float* bg1   = (const float*)d_in[11];
    const float* wg2   = (const float*)d_in[12];
    const float* bg2   = (const float*)d_in[13];

    int N = in_sizes[0];
    int E = in_sizes[2] / 2;
    const int* esrc = eidx;
    const int* edst = eidx + E;

    char* ws = (char*)d_ws;
    int*    cnt      = (int*)   (ws + 0x0);        // N ints
    int*    offs     = (int*)   (ws + 0x80000);    // N+1 ints
    int*    partials = (int*)   (ws + 0x100000);   // <=512 ints
    int*    cur      = (int*)   (ws + 0x110000);   // N+1 ints
    float*  dinv     = (float*) (ws + 0x180000);   // N floats
    int2*   cpack    = (int2*)  (ws + 0x200000);   // (E+N+8) int2 (~13.6 MB)
    __half* Ah       = (__half*)(ws + 0x1000000);  // N*128 halves (25.6 MB)
    __half* Bh       = (__half*)(ws + 0x2900000);  // N*128 halves (25.6 MB)
    float*  Of       = (float*) d_out;             // N*128 floats

    int nb = (N + 255) / 256;

    hipMemsetAsync(cnt, 0, (size_t)N * 4, stream);
    k_count<<<1024, 256, 0, stream>>>(edst, cnt, E);
    k_scan_a<<<nb, 256, 0, stream>>>(cnt, offs, partials, dinv, N);
    k_scan_b<<<1, 512, 0, stream>>>(partials, nb);
    k_scan_c<<<(N + 1 + 255) / 256, 256, 0, stream>>>(offs, partials, N, nb);
    hipMemcpyAsync(cur, offs, ((size_t)N + 1) * 4, hipMemcpyDeviceToDevice, stream);
    hipMemsetAsync(cpack + ((size_t)E + N), 0, 64, stream);   // pad for 8-wide over-read
    k_fill<<<1024, 256, 0, stream>>>(esrc, edst, cur, dinv, cpack, E);
    k_fill_loops<<<nb, 256, 0, stream>>>(cur, dinv, cpack, N);

    k_feat<<<(N + 3) / 4, 256, 0, stream>>>(label, bbox, emb, w1, b1, w2, b2, Ah, N);

    int fuse_grid = (N + 31) / 32;

    // layer 0: Bh = relu( agg(Ah) @ W0 + b0 )   (fp16 out)
    k_agg_gemm<1><<<fuse_grid, 256, 0, stream>>>((const uint4*)Ah, offs, cpack, wg0, bg0, Bh, N, 1);
    // layer 1: Ah = relu( agg(Bh) @ W1 + b1 )   (fp16 out)
    k_agg_gemm<1><<<fuse_grid, 256, 0, stream>>>((const uint4*)Bh, offs, cpack, wg1, bg1, Ah, N, 1);
    // layer 2: d_out = agg(Ah) @ W2 + b2        (fp32 out)
    k_agg_gemm<0><<<fuse_grid, 256, 0, stream>>>((const uint4*)Ah, offs, cpack, wg2, bg2, Of, N, 0);
}

// Round 6
// 515.428 us; speedup vs baseline: 1.2793x; 1.2793x over previous
//
#include <hip/hip_runtime.h>
#include <hip/hip_bf16.h>
#include <hip/hip_fp16.h>
#include <cstdint>
#include <cstddef>

typedef _Float16 h8 __attribute__((ext_vector_type(8)));
typedef float f4 __attribute__((ext_vector_type(4)));

// ---------------- CSR build ----------------

__global__ __launch_bounds__(256) void k_count(const int* __restrict__ dst, int* __restrict__ cnt, int E) {
    int i = blockIdx.x * blockDim.x + threadIdx.x;
    int stride = gridDim.x * blockDim.x;
    for (; i < E; i += stride) atomicAdd(&cnt[dst[i]], 1);
}

__global__ __launch_bounds__(256) void k_scan_a(const int* __restrict__ cnt, int* __restrict__ offs,
                                                int* __restrict__ partials, float* __restrict__ dinv, int N) {
    __shared__ int sh[256];
    int t = threadIdx.x;
    int i = blockIdx.x * 256 + t;
    int v = (i < N) ? (cnt[i] + 1) : 0;
    sh[t] = v;
    __syncthreads();
    for (int d = 1; d < 256; d <<= 1) {
        int add = (t >= d) ? sh[t - d] : 0;
        __syncthreads();
        sh[t] += add;
        __syncthreads();
    }
    if (i < N) {
        offs[i] = sh[t] - v;
        dinv[i] = rsqrtf((float)v);
    }
    if (t == 255) partials[blockIdx.x] = sh[255];
}

__global__ __launch_bounds__(512) void k_scan_b(int* __restrict__ partials, int nb) {
    __shared__ int sh[512];
    int t = threadIdx.x;
    int v = (t < nb) ? partials[t] : 0;
    sh[t] = v;
    __syncthreads();
    for (int d = 1; d < 512; d <<= 1) {
        int add = (t >= d) ? sh[t - d] : 0;
        __syncthreads();
        sh[t] += add;
        __syncthreads();
    }
    if (t < nb) partials[t] = sh[t];
}

__global__ __launch_bounds__(256) void k_scan_c(int* __restrict__ offs, const int* __restrict__ partials,
                                                int N, int nb) {
    int i = blockIdx.x * 256 + threadIdx.x;
    if (i < N) {
        int b = i >> 8;
        if (b > 0) offs[i] += partials[b - 1];
    } else if (i == N) {
        offs[N] = partials[nb - 1];
    }
}

__global__ __launch_bounds__(256) void k_fill(const int* __restrict__ src, const int* __restrict__ dst,
                                              int* __restrict__ cur,
                                              const float* __restrict__ dinv,
                                              int2* __restrict__ cpack, int E) {
    int i = blockIdx.x * blockDim.x + threadIdx.x;
    int stride = gridDim.x * blockDim.x;
    for (; i < E; i += stride) {
        int s = src[i], d = dst[i];
        int pos = atomicAdd(&cur[d], 1);
        cpack[pos] = make_int2(s, __float_as_int(dinv[s] * dinv[d]));
    }
}

__global__ __launch_bounds__(256) void k_fill_loops(int* __restrict__ cur,
                                                    const float* __restrict__ dinv,
                                                    int2* __restrict__ cpack, int N) {
    int i = blockIdx.x * blockDim.x + threadIdx.x;
    if (i < N) {
        int pos = atomicAdd(&cur[i], 1);
        float di = dinv[i];
        cpack[pos] = make_int2(i, __float_as_int(di * di));
    }
}

// ---------------- W -> W^T fp16 (once): WT[layer][c][k] = W_layer[k][c] ----------------

__global__ __launch_bounds__(256) void k_prep_w(const float* __restrict__ w0, const float* __restrict__ w1,
                                                const float* __restrict__ w2, _Float16* __restrict__ WT) {
    int idx = blockIdx.x * 256 + threadIdx.x;
    if (idx >= 3 * 16384) return;
    int l = idx >> 14, rem = idx & 16383, c = rem >> 7, k = rem & 127;
    const float* W = (l == 0) ? w0 : (l == 1) ? w1 : w2;
    WT[idx] = (_Float16)W[k * 128 + c];
}

// ---------------- node features: x = [emb[label], MLP(bbox)] -> fp16 ----------------

__global__ __launch_bounds__(256) void k_feat(const int* __restrict__ label, const float* __restrict__ bbox,
                                              const float* __restrict__ emb,
                                              const float* __restrict__ w1, const float* __restrict__ b1,
                                              const float* __restrict__ w2, const float* __restrict__ b2,
                                              __half* __restrict__ X, int N) {
    __shared__ float w1s[4 * 64];
    __shared__ float b1s[64], b2s[64];
    __shared__ float w2s[64 * 64];
    __shared__ float h1s[4][64];
    int t = threadIdx.x;
    if (t < 256) w1s[t] = w1[t];
    if (t < 64) { b1s[t] = b1[t]; b2s[t] = b2[t]; }
    for (int i = t; i < 64 * 64; i += 256) w2s[i] = w2[i];
    __syncthreads();

    int wave = t >> 6, lane = t & 63;
    int node = blockIdx.x * 4 + wave;
    bool ok = node < N;

    float h1 = 0.f;
    if (ok) {
        float bb0 = bbox[node * 4 + 0];
        float bb1 = bbox[node * 4 + 1];
        float bb2 = bbox[node * 4 + 2];
        float bb3 = bbox[node * 4 + 3];
        h1 = bb0 * w1s[0 * 64 + lane] + bb1 * w1s[1 * 64 + lane]
           + bb2 * w1s[2 * 64 + lane] + bb3 * w1s[3 * 64 + lane] + b1s[lane];
        h1 = fmaxf(h1, 0.f);
    }
    h1s[wave][lane] = h1;
    __syncthreads();

    if (ok) {
        float acc = b2s[lane];
        #pragma unroll 8
        for (int k = 0; k < 64; ++k) acc += h1s[wave][k] * w2s[k * 64 + lane];
        int lb = label[node];
        X[(size_t)node * 128 + lane] = __float2half(emb[(size_t)lb * 64 + lane]);
        X[(size_t)node * 128 + 64 + lane] = __float2half(acc);
    }
}

// ---------------- MFMA GEMM: H[N][128] = X[N][128] @ W  (fp16 in/out, fp32 acc) ----------------
// W passed pre-transposed fp16: WT[c][k]. Wave computes 16 rows x 128 cols via
// 8 col-tiles x 4 K-steps of mfma_f32_16x16x32_f16. A and B frags use the SAME
// (group q = lane>>4, elem j) -> k = q*8+j mapping, so any HW k-permutation cancels.
// C/D: col = lane&15, row = (lane>>4)*4 + reg  [m89-verified, dtype-independent].

__global__ __launch_bounds__(256) void k_gemm_mfma(const _Float16* __restrict__ X,
                                                   const _Float16* __restrict__ WT,
                                                   _Float16* __restrict__ H, int N) {
    int t = threadIdx.x;
    int wv = t >> 6, lane = t & 63;
    int r = lane & 15, q = lane >> 4;
    int n0 = blockIdx.x * 64 + wv * 16;

    int arow = n0 + r; if (arow > N - 1) arow = N - 1;   // clamp loads; stores guarded
    h8 a[4];
    #pragma unroll
    for (int s = 0; s < 4; ++s)
        a[s] = *(const h8*)&X[(size_t)arow * 128 + s * 32 + q * 8];

    #pragma unroll
    for (int ct = 0; ct < 8; ++ct) {
        h8 b[4];
        #pragma unroll
        for (int s = 0; s < 4; ++s)
            b[s] = *(const h8*)&WT[(size_t)(ct * 16 + r) * 128 + s * 32 + q * 8];
        f4 acc = {0.f, 0.f, 0.f, 0.f};
        #pragma unroll
        for (int s = 0; s < 4; ++s)
            acc = __builtin_amdgcn_mfma_f32_16x16x32_f16(a[s], b[s], acc, 0, 0, 0);
        #pragma unroll
        for (int i = 0; i < 4; ++i) {
            int row = n0 + q * 4 + i;
            if (row < N) H[(size_t)row * 128 + ct * 16 + r] = (_Float16)acc[i];
        }
    }
}

// ---------------- aggregation: Y[n] = relu?( sum_e norm_e * H[src_e] + b ) ----------------
// 1 wave per node, no LDS, fp16 rows (lane owns cols {2l,2l+1}), unroll-8 gathers.

template <int OUT_HALF>
__global__ __launch_bounds__(256) void k_agg(const __half2* __restrict__ H2, const int* __restrict__ offs,
                                             const int2* __restrict__ cpack,
                                             const float* __restrict__ bias, void* __restrict__ Yv,
                                             int N, int do_relu) {
    int node = blockIdx.x * 4 + (threadIdx.x >> 6);
    if (node >= N) return;
    int lane = threadIdx.x & 63;
    int i0 = offs[node], i1 = offs[node + 1];

    float2 acc = make_float2(0.f, 0.f);
    for (int base = i0; base < i1; base += 64) {
        int navail = i1 - base; if (navail > 64) navail = 64;
        int li = lane < navail ? lane : (navail - 1);
        int2 ep = cpack[base + li];
        for (int e = 0; e < navail; e += 8) {
            int s[8]; float w[8];
            #pragma unroll
            for (int j = 0; j < 8; ++j) {
                int idx = e + j;
                int cl = idx < navail ? idx : (navail - 1);
                s[j] = __shfl(ep.x, cl);
                float wj = __int_as_float(__shfl(ep.y, cl));
                w[j] = idx < navail ? wj : 0.f;
            }
            __half2 h[8];
            #pragma unroll
            for (int j = 0; j < 8; ++j) h[j] = H2[(size_t)s[j] * 64 + lane];
            #pragma unroll
            for (int j = 0; j < 8; ++j) {
                float2 f = __half22float2(h[j]);
                acc.x += f.x * w[j];
                acc.y += f.y * w[j];
            }
        }
    }

    float2 b = ((const float2*)bias)[lane];
    acc.x += b.x; acc.y += b.y;
    if (do_relu) { acc.x = fmaxf(acc.x, 0.f); acc.y = fmaxf(acc.y, 0.f); }

    if (OUT_HALF) {
        __half2 p = __float22half2_rn(acc);
        ((__half2*)Yv)[(size_t)node * 64 + lane] = p;
    } else {
        ((float2*)Yv)[(size_t)node * 64 + lane] = acc;
    }
}

// ---------------- launch ----------------

extern "C" void kernel_launch(void* const* d_in, const int* in_sizes, int n_in,
                              void* d_out, int out_size, void* d_ws, size_t ws_size,
                              hipStream_t stream) {
    const int*   label = (const int*)d_in[0];
    const float* bbox  = (const float*)d_in[1];
    const int*   eidx  = (const int*)d_in[2];
    const float* emb   = (const float*)d_in[3];
    const float* w1    = (const float*)d_in[4];
    const float* b1    = (const float*)d_in[5];
    const float* w2    = (const float*)d_in[6];
    const float* b2    = (const float*)d_in[7];
    const float* wg0   = (const float*)d_in[8];
    const float* bg0   = (const float*)d_in[9];
    const float* wg1   = (const float*)d_in[10];
    const float* bg1   = (const float*)d_in[11];
    const float* wg2   = (const float*)d_in[12];
    const float* bg2   = (const float*)d_in[13];

    int N = in_sizes[0];
    int E = in_sizes[2] / 2;
    const int* esrc = eidx;
    const int* edst = eidx + E;

    char* ws = (char*)d_ws;
    int*       cnt      = (int*)      (ws + 0x0);        // N ints
    int*       offs     = (int*)      (ws + 0x80000);    // N+1 ints
    int*       partials = (int*)      (ws + 0x100000);   // <=512 ints
    int*       cur      = (int*)      (ws + 0x110000);   // N+1 ints
    float*     dinv     = (float*)    (ws + 0x180000);   // N floats
    _Float16*  WT       = (_Float16*) (ws + 0x1C0000);   // 3*128*128 halves (96 KB)
    int2*      cpack    = (int2*)     (ws + 0x200000);   // (E+N+8) int2 (~13.6 MB)
    __half*    F0       = (__half*)   (ws + 0x1000000);  // N*128 halves (25.6 MB)
    __half*    G        = (__half*)   (ws + 0x2900000);  // N*128 halves (25.6 MB)
    __half*    F1       = (__half*)   d_out;             // fp16 scratch (layer-1 window only)
    float*     Of       = (float*)    d_out;             // final fp32 output

    int nb = (N + 255) / 256;

    hipMemsetAsync(cnt, 0, (size_t)N * 4, stream);
    k_count<<<1024, 256, 0, stream>>>(edst, cnt, E);
    k_scan_a<<<nb, 256, 0, stream>>>(cnt, offs, partials, dinv, N);
    k_scan_b<<<1, 512, 0, stream>>>(partials, nb);
    k_scan_c<<<(N + 1 + 255) / 256, 256, 0, stream>>>(offs, partials, N, nb);
    hipMemcpyAsync(cur, offs, ((size_t)N + 1) * 4, hipMemcpyDeviceToDevice, stream);
    hipMemsetAsync(cpack + ((size_t)E + N), 0, 64, stream);   // pad for 8-wide over-read
    k_fill<<<1024, 256, 0, stream>>>(esrc, edst, cur, dinv, cpack, E);
    k_fill_loops<<<nb, 256, 0, stream>>>(cur, dinv, cpack, N);

    k_prep_w<<<192, 256, 0, stream>>>(wg0, wg1, wg2, WT);
    k_feat<<<(N + 3) / 4, 256, 0, stream>>>(label, bbox, emb, w1, b1, w2, b2, F0, N);

    int gemm_grid = (N + 63) / 64;
    int agg_grid  = (N + 3) / 4;

    // layer 0: G = F0 @ W0 ; F1 = relu(A_hat G + b0)
    k_gemm_mfma<<<gemm_grid, 256, 0, stream>>>((const _Float16*)F0, WT + 0 * 16384, (_Float16*)G, N);
    k_agg<1><<<agg_grid, 256, 0, stream>>>((const __half2*)G, offs, cpack, bg0, F1, N, 1);
    // layer 1: G = F1 @ W1 ; F0 = relu(A_hat G + b1)
    k_gemm_mfma<<<gemm_grid, 256, 0, stream>>>((const _Float16*)F1, WT + 1 * 16384, (_Float16*)G, N);
    k_agg<1><<<agg_grid, 256, 0, stream>>>((const __half2*)G, offs, cpack, bg1, F0, N, 1);
    // layer 2: G = F0 @ W2 ; d_out = A_hat G + b2   (fp32)
    k_gemm_mfma<<<gemm_grid, 256, 0, stream>>>((const _Float16*)F0, WT + 2 * 16384, (_Float16*)G, N);
    k_agg<0><<<agg_grid, 256, 0, stream>>>((const __half2*)G, offs, cpack, bg2, Of, N, 0);
}

// Round 7
// 460.521 us; speedup vs baseline: 1.4319x; 1.1192x over previous
//
#include <hip/hip_runtime.h>
#include <hip/hip_bf16.h>
#include <hip/hip_fp16.h>
#include <cstdint>
#include <cstddef>

typedef _Float16 h8 __attribute__((ext_vector_type(8)));
typedef float f4 __attribute__((ext_vector_type(4)));

// ---------------- CSR build ----------------

// rank[i] = arrival order of edge i at its dst; cnt[d] = in-degree (excl. self-loop)
__global__ __launch_bounds__(256) void k_count_rank(const int* __restrict__ dst, int* __restrict__ cnt,
                                                    int* __restrict__ rank, int E) {
    int i = blockIdx.x * 256 + threadIdx.x;
    if (i < E) rank[i] = atomicAdd(&cnt[dst[i]], 1);
}

__global__ __launch_bounds__(256) void k_scan_a(const int* __restrict__ cnt, int* __restrict__ offs,
                                                int* __restrict__ partials, float* __restrict__ dinv, int N) {
    __shared__ int sh[256];
    int t = threadIdx.x;
    int i = blockIdx.x * 256 + t;
    int v = (i < N) ? (cnt[i] + 1) : 0;
    sh[t] = v;
    __syncthreads();
    for (int d = 1; d < 256; d <<= 1) {
        int add = (t >= d) ? sh[t - d] : 0;
        __syncthreads();
        sh[t] += add;
        __syncthreads();
    }
    if (i < N) {
        offs[i] = sh[t] - v;
        dinv[i] = rsqrtf((float)v);
    }
    if (t == 255) partials[blockIdx.x] = sh[255];
}

__global__ __launch_bounds__(512) void k_scan_b(int* __restrict__ partials, int nb) {
    __shared__ int sh[512];
    int t = threadIdx.x;
    int v = (t < nb) ? partials[t] : 0;
    sh[t] = v;
    __syncthreads();
    for (int d = 1; d < 512; d <<= 1) {
        int add = (t >= d) ? sh[t - d] : 0;
        __syncthreads();
        sh[t] += add;
        __syncthreads();
    }
    if (t < nb) partials[t] = sh[t];
}

__global__ __launch_bounds__(256) void k_scan_c(int* __restrict__ offs, const int* __restrict__ partials,
                                                int N, int nb) {
    int i = blockIdx.x * 256 + threadIdx.x;
    if (i < N) {
        int b = i >> 8;
        if (b > 0) offs[i] += partials[b - 1];
    } else if (i == N) {
        offs[N] = partials[nb - 1];
    }
}

// no atomic: pos = offs[dst] + rank; 1 edge per thread
__global__ __launch_bounds__(256) void k_fill2(const int* __restrict__ src, const int* __restrict__ dst,
                                               const int* __restrict__ rank, const int* __restrict__ offs,
                                               const float* __restrict__ dinv,
                                               int2* __restrict__ cpack, int E) {
    int i = blockIdx.x * 256 + threadIdx.x;
    if (i < E) {
        int s = src[i], d = dst[i];
        int pos = offs[d] + rank[i];
        cpack[pos] = make_int2(s, __float_as_int(dinv[s] * dinv[d]));
    }
}

// self-loop sits at the end of each node's segment: offs[i+1]-1
__global__ __launch_bounds__(256) void k_fill_loops(const int* __restrict__ offs,
                                                    const float* __restrict__ dinv,
                                                    int2* __restrict__ cpack, int N) {
    int i = blockIdx.x * 256 + threadIdx.x;
    if (i < N) {
        float di = dinv[i];
        cpack[offs[i + 1] - 1] = make_int2(i, __float_as_int(di * di));
    }
}

// ---------------- W -> W^T fp16 (once): WT[layer][c][k] = W_layer[k][c] ----------------

__global__ __launch_bounds__(256) void k_prep_w(const float* __restrict__ w0, const float* __restrict__ w1,
                                                const float* __restrict__ w2, _Float16* __restrict__ WT) {
    int idx = blockIdx.x * 256 + threadIdx.x;
    if (idx >= 3 * 16384) return;
    int l = idx >> 14, rem = idx & 16383, c = rem >> 7, k = rem & 127;
    const float* W = (l == 0) ? w0 : (l == 1) ? w1 : w2;
    WT[idx] = (_Float16)W[k * 128 + c];
}

// ---------------- node features: x = [emb[label], MLP(bbox)] -> fp16 ----------------

__global__ __launch_bounds__(256) void k_feat(const int* __restrict__ label, const float* __restrict__ bbox,
                                              const float* __restrict__ emb,
                                              const float* __restrict__ w1, const float* __restrict__ b1,
                                              const float* __restrict__ w2, const float* __restrict__ b2,
                                              __half* __restrict__ X, int N) {
    __shared__ float w1s[4 * 64];
    __shared__ float b1s[64], b2s[64];
    __shared__ float w2s[64 * 64];
    __shared__ float h1s[4][64];
    int t = threadIdx.x;
    if (t < 256) w1s[t] = w1[t];
    if (t < 64) { b1s[t] = b1[t]; b2s[t] = b2[t]; }
    for (int i = t; i < 64 * 64; i += 256) w2s[i] = w2[i];
    __syncthreads();

    int wave = t >> 6, lane = t & 63;
    int node = blockIdx.x * 4 + wave;
    bool ok = node < N;

    float h1 = 0.f;
    if (ok) {
        float bb0 = bbox[node * 4 + 0];
        float bb1 = bbox[node * 4 + 1];
        float bb2 = bbox[node * 4 + 2];
        float bb3 = bbox[node * 4 + 3];
        h1 = bb0 * w1s[0 * 64 + lane] + bb1 * w1s[1 * 64 + lane]
           + bb2 * w1s[2 * 64 + lane] + bb3 * w1s[3 * 64 + lane] + b1s[lane];
        h1 = fmaxf(h1, 0.f);
    }
    h1s[wave][lane] = h1;
    __syncthreads();

    if (ok) {
        float acc = b2s[lane];
        #pragma unroll 8
        for (int k = 0; k < 64; ++k) acc += h1s[wave][k] * w2s[k * 64 + lane];
        int lb = label[node];
        X[(size_t)node * 128 + lane] = __float2half(emb[(size_t)lb * 64 + lane]);
        X[(size_t)node * 128 + 64 + lane] = __float2half(acc);
    }
}

// ---------------- MFMA GEMM: H[N][128] = X[N][128] @ W  (fp16 in/out, fp32 acc) ----------------

__global__ __launch_bounds__(256) void k_gemm_mfma(const _Float16* __restrict__ X,
                                                   const _Float16* __restrict__ WT,
                                                   _Float16* __restrict__ H, int N) {
    int t = threadIdx.x;
    int wv = t >> 6, lane = t & 63;
    int r = lane & 15, q = lane >> 4;
    int n0 = blockIdx.x * 64 + wv * 16;

    int arow = n0 + r; if (arow > N - 1) arow = N - 1;
    h8 a[4];
    #pragma unroll
    for (int s = 0; s < 4; ++s)
        a[s] = *(const h8*)&X[(size_t)arow * 128 + s * 32 + q * 8];

    #pragma unroll
    for (int ct = 0; ct < 8; ++ct) {
        h8 b[4];
        #pragma unroll
        for (int s = 0; s < 4; ++s)
            b[s] = *(const h8*)&WT[(size_t)(ct * 16 + r) * 128 + s * 32 + q * 8];
        f4 acc = {0.f, 0.f, 0.f, 0.f};
        #pragma unroll
        for (int s = 0; s < 4; ++s)
            acc = __builtin_amdgcn_mfma_f32_16x16x32_f16(a[s], b[s], acc, 0, 0, 0);
        #pragma unroll
        for (int i = 0; i < 4; ++i) {
            int row = n0 + q * 4 + i;
            if (row < N) H[(size_t)row * 128 + ct * 16 + r] = (_Float16)acc[i];
        }
    }
}

// ---------------- aggregation: Y[n] = relu?( sum_e norm_e * H[src_e] + b ) ----------------
// 1 wave per node; 4 groups x 16 lanes. Group g gathers edges {e+4g..e+4g+3} as
// dwordx4 (16 lanes x 16 B = full 256 B row per edge); (s,w) broadcast via shfl;
// cross-group shfl_xor reduce once per node. Group 0 writes the row.

template <int OUT_HALF>
__global__ __launch_bounds__(256) void k_agg(const uint4* __restrict__ H4, const int* __restrict__ offs,
                                             const int2* __restrict__ cpack,
                                             const float* __restrict__ bias, void* __restrict__ Yv,
                                             int N, int do_relu) {
    int node = blockIdx.x * 4 + (threadIdx.x >> 6);
    if (node >= N) return;
    int lane = threadIdx.x & 63;
    int grp = lane >> 4, li = lane & 15;
    int i0 = offs[node], i1 = offs[node + 1];

    float acc[8];
    #pragma unroll
    for (int k = 0; k < 8; ++k) acc[k] = 0.f;

    for (int base = i0; base < i1; base += 64) {
        int navail = i1 - base; if (navail > 64) navail = 64;
        int lidx = lane < navail ? lane : (navail - 1);
        int2 ep = cpack[base + lidx];
        for (int e = 0; e < navail; e += 16) {
            int s[4]; float w[4];
            #pragma unroll
            for (int j = 0; j < 4; ++j) {
                int idx = e + 4 * grp + j;
                int cl = idx < navail ? idx : (navail - 1);
                s[j] = __shfl(ep.x, cl);
                float wj = __int_as_float(__shfl(ep.y, cl));
                w[j] = idx < navail ? wj : 0.f;
            }
            uint4 h[4];
            #pragma unroll
            for (int j = 0; j < 4; ++j) h[j] = H4[(size_t)s[j] * 16 + li];
            #pragma unroll
            for (int j = 0; j < 4; ++j) {
                float2 f;
                f = __half22float2(*(const __half2*)&h[j].x); acc[0] += f.x * w[j]; acc[1] += f.y * w[j];
                f = __half22float2(*(const __half2*)&h[j].y); acc[2] += f.x * w[j]; acc[3] += f.y * w[j];
                f = __half22float2(*(const __half2*)&h[j].z); acc[4] += f.x * w[j]; acc[5] += f.y * w[j];
                f = __half22float2(*(const __half2*)&h[j].w); acc[6] += f.x * w[j]; acc[7] += f.y * w[j];
            }
        }
    }

    // lanes l, l^16, l^32, l^48 hold partials of the same 8 columns
    #pragma unroll
    for (int k = 0; k < 8; ++k) {
        float v = acc[k];
        v += __shfl_xor(v, 16);
        v += __shfl_xor(v, 32);
        acc[k] = v;
    }

    if (grp == 0) {
        float4 b0 = *(const float4*)&bias[li * 8];
        float4 b1 = *(const float4*)&bias[li * 8 + 4];
        acc[0] += b0.x; acc[1] += b0.y; acc[2] += b0.z; acc[3] += b0.w;
        acc[4] += b1.x; acc[5] += b1.y; acc[6] += b1.z; acc[7] += b1.w;
        if (do_relu) {
            #pragma unroll
            for (int k = 0; k < 8; ++k) acc[k] = fmaxf(acc[k], 0.f);
        }
        if (OUT_HALF) {
            __half2 p0 = __float22half2_rn(make_float2(acc[0], acc[1]));
            __half2 p1 = __float22half2_rn(make_float2(acc[2], acc[3]));
            __half2 p2 = __float22half2_rn(make_float2(acc[4], acc[5]));
            __half2 p3 = __float22half2_rn(make_float2(acc[6], acc[7]));
            uint4 pk;
            pk.x = *(unsigned int*)&p0; pk.y = *(unsigned int*)&p1;
            pk.z = *(unsigned int*)&p2; pk.w = *(unsigned int*)&p3;
            ((uint4*)Yv)[(size_t)node * 16 + li] = pk;
        } else {
            float* Yf = (float*)Yv;
            *(float4*)&Yf[(size_t)node * 128 + li * 8]     = make_float4(acc[0], acc[1], acc[2], acc[3]);
            *(float4*)&Yf[(size_t)node * 128 + li * 8 + 4] = make_float4(acc[4], acc[5], acc[6], acc[7]);
        }
    }
}

// ---------------- launch ----------------

extern "C" void kernel_launch(void* const* d_in, const int* in_sizes, int n_in,
                              void* d_out, int out_size, void* d_ws, size_t ws_size,
                              hipStream_t stream) {
    const int*   label = (const int*)d_in[0];
    const float* bbox  = (const float*)d_in[1];
    const int*   eidx  = (const int*)d_in[2];
    const float* emb   = (const float*)d_in[3];
    const float* w1    = (const float*)d_in[4];
    const float* b1    = (const float*)d_in[5];
    const float* w2    = (const float*)d_in[6];
    const float* b2    = (const float*)d_in[7];
    const float* wg0   = (const float*)d_in[8];
    const float* bg0   = (const float*)d_in[9];
    const float* wg1   = (const float*)d_in[10];
    const float* bg1   = (const float*)d_in[11];
    const float* wg2   = (const float*)d_in[12];
    const float* bg2   = (const float*)d_in[13];

    int N = in_sizes[0];
    int E = in_sizes[2] / 2;
    const int* esrc = eidx;
    const int* edst = eidx + E;

    char* ws = (char*)d_ws;
    int*       cnt      = (int*)      (ws + 0x0);        // N ints
    int*       offs     = (int*)      (ws + 0x80000);    // N+1 ints
    int*       partials = (int*)      (ws + 0x100000);   // <=512 ints
    float*     dinv     = (float*)    (ws + 0x180000);   // N floats
    _Float16*  WT       = (_Float16*) (ws + 0x1C0000);   // 3*128*128 halves (96 KB)
    int2*      cpack    = (int2*)     (ws + 0x200000);   // (E+N) int2 (~13.6 MB)
    __half*    F0       = (__half*)   (ws + 0x1000000);  // N*128 halves (25.6 MB)
    int*       rank     = (int*)      (ws + 0x1000000);  // E ints — aliases F0 (dead before k_feat)
    __half*    G        = (__half*)   (ws + 0x2900000);  // N*128 halves (25.6 MB)
    __half*    F1       = (__half*)   d_out;             // fp16 scratch (layer-1 window only)
    float*     Of       = (float*)    d_out;             // final fp32 output

    int nb = (N + 255) / 256;
    int eb = (E + 255) / 256;

    hipMemsetAsync(cnt, 0, (size_t)N * 4, stream);
    k_count_rank<<<eb, 256, 0, stream>>>(edst, cnt, rank, E);
    k_scan_a<<<nb, 256, 0, stream>>>(cnt, offs, partials, dinv, N);
    k_scan_b<<<1, 512, 0, stream>>>(partials, nb);
    k_scan_c<<<(N + 1 + 255) / 256, 256, 0, stream>>>(offs, partials, N, nb);
    k_fill2<<<eb, 256, 0, stream>>>(esrc, edst, rank, offs, dinv, cpack, E);
    k_fill_loops<<<nb, 256, 0, stream>>>(offs, dinv, cpack, N);

    k_prep_w<<<192, 256, 0, stream>>>(wg0, wg1, wg2, WT);
    k_feat<<<(N + 3) / 4, 256, 0, stream>>>(label, bbox, emb, w1, b1, w2, b2, F0, N);

    int gemm_grid = (N + 63) / 64;
    int agg_grid  = (N + 3) / 4;

    // layer 0: G = F0 @ W0 ; F1 = relu(A_hat G + b0)
    k_gemm_mfma<<<gemm_grid, 256, 0, stream>>>((const _Float16*)F0, WT + 0 * 16384, (_Float16*)G, N);
    k_agg<1><<<agg_grid, 256, 0, stream>>>((const uint4*)G, offs, cpack, bg0, F1, N, 1);
    // layer 1: G = F1 @ W1 ; F0 = relu(A_hat G + b1)
    k_gemm_mfma<<<gemm_grid, 256, 0, stream>>>((const _Float16*)F1, WT + 1 * 16384, (_Float16*)G, N);
    k_agg<1><<<agg_grid, 256, 0, stream>>>((const uint4*)G, offs, cpack, bg1, F0, N, 1);
    // layer 2: G = F0 @ W2 ; d_out = A_hat G + b2   (fp32)
    k_gemm_mfma<<<gemm_grid, 256, 0, stream>>>((const _Float16*)F0, WT + 2 * 16384, (_Float16*)G, N);
    k_agg<0><<<agg_grid, 256, 0, stream>>>((const uint4*)G, offs, cpack, bg2, Of, N, 0);
}